// Round 1
// baseline (181.187 us; speedup 1.0000x reference)
//
#include <hip/hip_runtime.h>

#define B_ 64
#define N_ 64
#define D_ 256
#define LAP_ 16
#define M_ 2016           // 64*63/2
#define TOK_ 2081         // 1 + 64 + 2016

// ---------------------------------------------------------------------------
// Kernel 1: stable compaction. One block per batch, 256 threads, 8 edges/thread.
// pack[b*M + p] = i | (j<<8) | (valid<<16)
// ---------------------------------------------------------------------------
__global__ __launch_bounds__(256) void compact_kernel(const int* __restrict__ adj,
                                                      int* __restrict__ pack) {
    int b = blockIdx.x;
    int t = threadIdx.x;
    __shared__ int s[256];
    __shared__ int s_total;

    int ii[8], jj[8], vv[8];
    int c = 0;
#pragma unroll
    for (int k = 0; k < 8; k++) {
        int m = t * 8 + k;
        int valid = 0, i = 0, j = 0;
        if (m < M_) {
            // row i: off(i) = (127*i - i*i)/2, find largest i with off(i) <= m
            float fm = (float)m;
            int gi = (int)((127.0f - sqrtf(127.0f * 127.0f - 8.0f * fm)) * 0.5f);
            if (gi < 0) gi = 0;
            if (gi > 62) gi = 62;
            while (gi > 0 && (127 * gi - gi * gi) / 2 > m) gi--;
            while (gi < 62 && (127 * (gi + 1) - (gi + 1) * (gi + 1)) / 2 <= m) gi++;
            i = gi;
            j = i + 1 + (m - (127 * i - i * i) / 2);
            valid = (adj[b * (N_ * N_) + i * N_ + j] > 0) ? 1 : 0;
        }
        ii[k] = i; jj[k] = j; vv[k] = valid;
        c += valid;
    }
    s[t] = c;
    __syncthreads();
    // inclusive Hillis-Steele scan over 256 thread-counts
    for (int off = 1; off < 256; off <<= 1) {
        int v = (t >= off) ? s[t - off] : 0;
        __syncthreads();
        s[t] += v;
        __syncthreads();
    }
    if (t == 255) s_total = s[255];
    __syncthreads();
    int total = s_total;
    int run = s[t] - c;  // exclusive prefix: #valid with index < t*8
#pragma unroll
    for (int k = 0; k < 8; k++) {
        int m = t * 8 + k;
        if (m < M_) {
            int p;
            if (vv[k]) { p = run; run++; }
            else       { p = total + (m - run); }
            pack[b * M_ + p] = ii[k] | (jj[k] << 8) | (vv[k] << 16);
        }
    }
}

// ---------------------------------------------------------------------------
// Kernel 2: graph token + pad_mask[: , 0..64] = 0. One block per batch.
// ---------------------------------------------------------------------------
__global__ __launch_bounds__(256) void head_kernel(const float* __restrict__ graph_tok,
                                                   float* __restrict__ out) {
    int b = blockIdx.x;
    int t = threadIdx.x;
    out[(size_t)b * TOK_ * D_ + t] = graph_tok[t];
    float* mask = out + (size_t)B_ * TOK_ * D_;
    if (t < 1 + N_) mask[b * TOK_ + t] = 0.0f;
}

// ---------------------------------------------------------------------------
// Kernel 3: node tokens. Grid (B, 16), 4 nodes/block (one wave per node).
// out[b, 1+n, :] = node_feats[b,n,:] + sum_l eigvec[b,n,l] * W_lap[l,:]
// ---------------------------------------------------------------------------
__global__ __launch_bounds__(256) void node_kernel(const float* __restrict__ node_feats,
                                                   const float* __restrict__ eigvec,
                                                   const float* __restrict__ W_lap,
                                                   float* __restrict__ out) {
    int b = blockIdx.x;
    int n = blockIdx.y * 4 + (threadIdx.x >> 6);
    int lane = threadIdx.x & 63;
    const float* e = eigvec + (size_t)(b * N_ + n) * LAP_;
    float4 acc = ((const float4*)(node_feats + ((size_t)b * N_ + n) * D_))[lane];
#pragma unroll
    for (int l = 0; l < LAP_; l++) {
        float el = e[l];
        float4 w = ((const float4*)(W_lap + l * D_))[lane];
        acc.x += el * w.x; acc.y += el * w.y; acc.z += el * w.z; acc.w += el * w.w;
    }
    ((float4*)(out + (size_t)b * TOK_ * D_ + (size_t)(1 + n) * D_))[lane] = acc;
}

// ---------------------------------------------------------------------------
// Kernel 4: edge tokens. Grid (B, 63), 256 threads, 32 tokens/block, 8/wave.
// LDS: W_edge rows 1..32 (32KB) + fused base row (1KB) + batch eigvec (4KB).
// ---------------------------------------------------------------------------
__global__ __launch_bounds__(256) void edge_kernel(const float* __restrict__ eigvec,
                                                   const float* __restrict__ W_edge,
                                                   const float* __restrict__ b_edge,
                                                   const float* __restrict__ type_embed,
                                                   const int* __restrict__ pack,
                                                   float* __restrict__ out) {
    __shared__ float sW[32 * D_];     // rows 1..32 of W_edge
    __shared__ float sBase[D_];       // W_edge[0] + b_edge + type_embed[1]
    __shared__ float sEig[N_ * LAP_]; // this batch's eigvec

    int b = blockIdx.x;
    int t = threadIdx.x;

    sBase[t] = W_edge[t] + b_edge[t] + type_embed[D_ + t];
    {
        const float4* src = (const float4*)(W_edge + D_);
        float4* dst = (float4*)sW;
#pragma unroll
        for (int k = 0; k < 8; k++) dst[t + 256 * k] = src[t + 256 * k];
        ((float4*)sEig)[t] = ((const float4*)(eigvec + (size_t)b * N_ * LAP_))[t];
    }
    __syncthreads();

    int wave = t >> 6, lane = t & 63;
    float* maskb = out + (size_t)B_ * TOK_ * D_ + (size_t)b * TOK_ + 1 + N_;
    float* outb = out + (size_t)b * TOK_ * D_ + (size_t)(1 + N_) * D_;

#pragma unroll
    for (int k = 0; k < 8; k++) {
        int p = blockIdx.y * 32 + wave * 8 + k;
        int pk = pack[b * M_ + p];
        float4 acc = make_float4(0.f, 0.f, 0.f, 0.f);
        int valid = (pk >> 16) & 1;
        if (valid) {
            int si = pk & 0xff, di = (pk >> 8) & 0xff;
            const float* eu = sEig + si * LAP_;
            const float* ev = sEig + di * LAP_;
            acc = ((float4*)sBase)[lane];
#pragma unroll
            for (int l = 0; l < LAP_; l++) {
                float pu = eu[l], pv = ev[l];
                float4 w1 = ((float4*)(sW + l * D_))[lane];
                float4 w2 = ((float4*)(sW + (LAP_ + l) * D_))[lane];
                acc.x += pu * w1.x + pv * w2.x;
                acc.y += pu * w1.y + pv * w2.y;
                acc.z += pu * w1.z + pv * w2.z;
                acc.w += pu * w1.w + pv * w2.w;
            }
        }
        ((float4*)(outb + (size_t)p * D_))[lane] = acc;
        if (lane == 0) maskb[p] = valid ? 0.0f : 1.0f;
    }
}

extern "C" void kernel_launch(void* const* d_in, const int* in_sizes, int n_in,
                              void* d_out, int out_size, void* d_ws, size_t ws_size,
                              hipStream_t stream) {
    const int*   adj        = (const int*)d_in[0];
    const float* node_feats = (const float*)d_in[1];
    const float* eigvec     = (const float*)d_in[2];
    const float* W_lap      = (const float*)d_in[3];
    const float* W_edge     = (const float*)d_in[4];
    const float* b_edge     = (const float*)d_in[5];
    const float* type_embed = (const float*)d_in[6];
    const float* graph_tok  = (const float*)d_in[7];
    float* out = (float*)d_out;
    int* pack = (int*)d_ws;  // B*M ints = 516 KB

    compact_kernel<<<dim3(B_), dim3(256), 0, stream>>>(adj, pack);
    head_kernel<<<dim3(B_), dim3(256), 0, stream>>>(graph_tok, out);
    node_kernel<<<dim3(B_, 16), dim3(256), 0, stream>>>(node_feats, eigvec, W_lap, out);
    edge_kernel<<<dim3(B_, 63), dim3(256), 0, stream>>>(eigvec, W_edge, b_edge,
                                                        type_embed, pack, out);
}

// Round 2
// 179.534 us; speedup vs baseline: 1.0092x; 1.0092x over previous
//
#include <hip/hip_runtime.h>

#define B_ 64
#define N_ 64
#define D_ 256
#define LAP_ 16
#define M_ 2016           // 64*63/2
#define TOK_ 2081         // 1 + 64 + 2016

// ---------------------------------------------------------------------------
// Kernel 1: stable compaction. One block per batch, 256 threads, 8 edges/thread.
// pack[b*M + p] = i | (j<<8) | (valid<<16)
// ---------------------------------------------------------------------------
__global__ __launch_bounds__(256) void compact_kernel(const int* __restrict__ adj,
                                                      int* __restrict__ pack) {
    int b = blockIdx.x;
    int t = threadIdx.x;
    __shared__ int s[256];
    __shared__ int s_total;

    int ii[8], jj[8], vv[8];
    int c = 0;
#pragma unroll
    for (int k = 0; k < 8; k++) {
        int m = t * 8 + k;
        int valid = 0, i = 0, j = 0;
        if (m < M_) {
            // row i: off(i) = (127*i - i*i)/2, find largest i with off(i) <= m
            float fm = (float)m;
            int gi = (int)((127.0f - sqrtf(127.0f * 127.0f - 8.0f * fm)) * 0.5f);
            if (gi < 0) gi = 0;
            if (gi > 62) gi = 62;
            while (gi > 0 && (127 * gi - gi * gi) / 2 > m) gi--;
            while (gi < 62 && (127 * (gi + 1) - (gi + 1) * (gi + 1)) / 2 <= m) gi++;
            i = gi;
            j = i + 1 + (m - (127 * i - i * i) / 2);
            valid = (adj[b * (N_ * N_) + i * N_ + j] > 0) ? 1 : 0;
        }
        ii[k] = i; jj[k] = j; vv[k] = valid;
        c += valid;
    }
    s[t] = c;
    __syncthreads();
    // inclusive Hillis-Steele scan over 256 thread-counts
    for (int off = 1; off < 256; off <<= 1) {
        int v = (t >= off) ? s[t - off] : 0;
        __syncthreads();
        s[t] += v;
        __syncthreads();
    }
    if (t == 255) s_total = s[255];
    __syncthreads();
    int total = s_total;
    int run = s[t] - c;  // exclusive prefix: #valid with index < t*8
#pragma unroll
    for (int k = 0; k < 8; k++) {
        int m = t * 8 + k;
        if (m < M_) {
            int p;
            if (vv[k]) { p = run; run++; }
            else       { p = total + (m - run); }
            pack[b * M_ + p] = ii[k] | (jj[k] << 8) | (vv[k] << 16);
        }
    }
}

// ---------------------------------------------------------------------------
// Kernel 2: node tokens + graph token + head of pad_mask.
// Grid (B, 16), 4 nodes/block (one wave per node).
// out[b, 1+n, :] = node_feats[b,n,:] + sum_l eigvec[b,n,l] * W_lap[l,:]
// blockIdx.y==0 additionally writes out[b,0,:]=graph_tok and mask[b,0..64]=0.
// ---------------------------------------------------------------------------
__global__ __launch_bounds__(256) void node_kernel(const float* __restrict__ node_feats,
                                                   const float* __restrict__ eigvec,
                                                   const float* __restrict__ W_lap,
                                                   const float* __restrict__ graph_tok,
                                                   float* __restrict__ out) {
    int b = blockIdx.x;
    int t = threadIdx.x;
    int n = blockIdx.y * 4 + (t >> 6);
    int lane = t & 63;
    const float* e = eigvec + (size_t)(b * N_ + n) * LAP_;
    float4 acc = ((const float4*)(node_feats + ((size_t)b * N_ + n) * D_))[lane];
#pragma unroll
    for (int l = 0; l < LAP_; l++) {
        float el = e[l];
        float4 w = ((const float4*)(W_lap + l * D_))[lane];
        acc.x += el * w.x; acc.y += el * w.y; acc.z += el * w.z; acc.w += el * w.w;
    }
    ((float4*)(out + (size_t)b * TOK_ * D_ + (size_t)(1 + n) * D_))[lane] = acc;

    if (blockIdx.y == 0) {
        out[(size_t)b * TOK_ * D_ + t] = graph_tok[t];
        float* mask = out + (size_t)B_ * TOK_ * D_;
        if (t < 1 + N_) mask[b * TOK_ + t] = 0.0f;
    }
}

// ---------------------------------------------------------------------------
// Kernel 3: edge tokens, register-resident weights.
// Grid (B, 63), 256 threads, 32 tokens/block, 8 tokens/wave.
// Each lane owns 4 output columns; W1/W2 slices (16 float4 each) live in VGPRs.
// Per token: 8 uniform ds_read_b128 (eigvec rows) + 128 FMA + 1 store_dwordx4.
// ---------------------------------------------------------------------------
__global__ __launch_bounds__(256) void edge_kernel(const float* __restrict__ eigvec,
                                                   const float* __restrict__ W_edge,
                                                   const float* __restrict__ b_edge,
                                                   const float* __restrict__ type_embed,
                                                   const int* __restrict__ pack,
                                                   float* __restrict__ out) {
    __shared__ float sEig[N_ * LAP_]; // 4 KB: this batch's eigvec

    int b = blockIdx.x;
    int t = threadIdx.x;
    int wave = t >> 6, lane = t & 63;

    ((float4*)sEig)[t] = ((const float4*)(eigvec + (size_t)b * N_ * LAP_))[t];

    // register-resident weights: lane owns columns [4*lane, 4*lane+4)
    float4 base = ((const float4*)W_edge)[lane];
    {
        float4 bb = ((const float4*)b_edge)[lane];
        float4 te = ((const float4*)(type_embed + D_))[lane];
        base.x += bb.x + te.x; base.y += bb.y + te.y;
        base.z += bb.z + te.z; base.w += bb.w + te.w;
    }
    float4 w1[LAP_], w2[LAP_];
#pragma unroll
    for (int l = 0; l < LAP_; l++) {
        w1[l] = ((const float4*)(W_edge + (1 + l) * D_))[lane];
        w2[l] = ((const float4*)(W_edge + (1 + LAP_ + l) * D_))[lane];
    }
    __syncthreads();

    float* maskb = out + (size_t)B_ * TOK_ * D_ + (size_t)b * TOK_ + 1 + N_;
    float* outb = out + (size_t)b * TOK_ * D_ + (size_t)(1 + N_) * D_;

#pragma unroll
    for (int k = 0; k < 8; k++) {
        int p = blockIdx.y * 32 + wave * 8 + k;
        int pk = pack[b * M_ + p];
        float4 acc = make_float4(0.f, 0.f, 0.f, 0.f);
        int valid = (pk >> 16) & 1;
        if (valid) {
            int si = pk & 0xff, di = (pk >> 8) & 0xff;
            const float4* eu4 = (const float4*)(sEig + si * LAP_);
            const float4* ev4 = (const float4*)(sEig + di * LAP_);
            float4 eu[4], ev[4];
#pragma unroll
            for (int q = 0; q < 4; q++) { eu[q] = eu4[q]; ev[q] = ev4[q]; }
            acc = base;
            const float* euf = (const float*)eu;
            const float* evf = (const float*)ev;
#pragma unroll
            for (int l = 0; l < LAP_; l++) {
                float pu = euf[l], pv = evf[l];
                acc.x += pu * w1[l].x + pv * w2[l].x;
                acc.y += pu * w1[l].y + pv * w2[l].y;
                acc.z += pu * w1[l].z + pv * w2[l].z;
                acc.w += pu * w1[l].w + pv * w2[l].w;
            }
        }
        ((float4*)(outb + (size_t)p * D_))[lane] = acc;
        if (lane == 0) maskb[p] = valid ? 0.0f : 1.0f;
    }
}

extern "C" void kernel_launch(void* const* d_in, const int* in_sizes, int n_in,
                              void* d_out, int out_size, void* d_ws, size_t ws_size,
                              hipStream_t stream) {
    const int*   adj        = (const int*)d_in[0];
    const float* node_feats = (const float*)d_in[1];
    const float* eigvec     = (const float*)d_in[2];
    const float* W_lap      = (const float*)d_in[3];
    const float* W_edge     = (const float*)d_in[4];
    const float* b_edge     = (const float*)d_in[5];
    const float* type_embed = (const float*)d_in[6];
    const float* graph_tok  = (const float*)d_in[7];
    float* out = (float*)d_out;
    int* pack = (int*)d_ws;  // B*M ints = 516 KB

    compact_kernel<<<dim3(B_), dim3(256), 0, stream>>>(adj, pack);
    node_kernel<<<dim3(B_, 16), dim3(256), 0, stream>>>(node_feats, eigvec, W_lap,
                                                        graph_tok, out);
    edge_kernel<<<dim3(B_, 63), dim3(256), 0, stream>>>(eigvec, W_edge, b_edge,
                                                        type_embed, pack, out);
}